// Round 12
// baseline (433.456 us; speedup 1.0000x reference)
//
#include <hip/hip_runtime.h>
#include <hip/hip_bf16.h>
#include <math.h>

#define H 128
#define SB 64      // scan blocks (spatial relation)
#define NSLICE 32  // front-kernel role-interleave slices

typedef float f32x4 __attribute__((ext_vector_type(4)));
typedef __bf16 bf16x8 __attribute__((ext_vector_type(8)));

__device__ __forceinline__ unsigned short f2bf(float f) {
    return __builtin_bit_cast(unsigned short, (__bf16)f);
}
__device__ __forceinline__ unsigned pack2(float lo, float hi) {
    return (unsigned)f2bf(lo) | ((unsigned)f2bf(hi) << 16);
}
__device__ __forceinline__ void acc2(unsigned u, float& a, float& b) {
    union { unsigned u; float f; } x, y;
    x.u = u << 16; y.u = u & 0xffff0000u;
    a += x.f; b += y.f;
}
__device__ __forceinline__ float bflo(unsigned u) {
    union { unsigned u; float f; } x; x.u = u << 16; return x.f;
}
__device__ __forceinline__ float bfhi(unsigned u) {
    union { unsigned u; float f; } x; x.u = u & 0xffff0000u; return x.f;
}

// ================= fused front: role-INTERLEAVED scatter + count + encoder =================
__global__ __launch_bounds__(256) void k_front(
    const int* __restrict__ s0, const int* __restrict__ s1,
    const int* __restrict__ s2, const int* __restrict__ s3,
    const float* __restrict__ xL, const float* __restrict__ xS, const float* __restrict__ xI,
    const float* __restrict__ x_int, const float* __restrict__ W_int, const float* __restrict__ b_int,
    int E0, int E1, int E2, int E3,
    int g1, int g2, int g3, int g4, int Btot, int chunk,
    float* __restrict__ XL, float* __restrict__ XS, float* __restrict__ XI,
    float* __restrict__ CNT1, float* __restrict__ CNT2, float* __restrict__ CNT3,
    int* __restrict__ cnt0, int* __restrict__ seq,
    unsigned short* __restrict__ hb, int n)
{
    __shared__ __align__(16) char WB[128 * 80];   // used by encoder blocks only
    // bijective slice permutation: consecutive HW blocks hit different role segments
    int hw = blockIdx.x;
    int b = (hw % NSLICE) * chunk + hw / NSLICE;
    if (b >= Btot) return;
    int tid = threadIdx.x;

    if (b < g1) {
        // ---- lane relation: D=16, 16 lanes/edge, 16 edges/block ----
        int e = b * 16 + (tid >> 4);
        if (e >= E1) return;
        int d = tid & 15;
        int src = s1[e], tgt = s1[E1 + e];
        unsafeAtomicAdd(&XL[(size_t)tgt * 16 + d], xL[(size_t)src * 16 + d]);
        if (d == 0) unsafeAtomicAdd(&CNT1[tgt], 1.0f);
        return;
    }
    if (b < g2) {
        // ---- sens relation: D=8, 8 lanes/edge, 32 edges/block ----
        int e = (b - g1) * 32 + (tid >> 3);
        if (e >= E2) return;
        int d = tid & 7;
        int src = s2[e], tgt = s2[E2 + e];
        unsafeAtomicAdd(&XS[(size_t)tgt * 8 + d], xS[(size_t)src * 8 + d]);
        if (d == 0) unsafeAtomicAdd(&CNT2[tgt], 1.0f);
        return;
    }
    if (b < g3) {
        // ---- inj relation: D=8 ----
        int e = (b - g2) * 32 + (tid >> 3);
        if (e >= E3) return;
        int d = tid & 7;
        int src = s3[e], tgt = s3[E3 + e];
        unsafeAtomicAdd(&XI[(size_t)tgt * 8 + d], xI[(size_t)src * 8 + d]);
        if (d == 0) unsafeAtomicAdd(&CNT3[tgt], 1.0f);
        return;
    }
    if (b < g4) {
        // ---- spatial count + seq ----
        int e = (b - g3) * 256 + tid;
        if (e >= E0) return;
        seq[e] = atomicAdd(&cnt0[s0[E0 + e]], 1);
        return;
    }

    // ---- x_int MFMA encoder (K=32) ----
    int eb = b - g4;
    {
        int c = tid & 127, khalf = tid >> 7;
        for (int kk = 0; kk < 16; ++kk) {
            int k = khalf * 16 + kk;
            *(unsigned short*)(WB + c * 80 + k * 2) = f2bf(W_int[(size_t)k * H + c]);
        }
    }
    int lane = tid & 63, wv = tid >> 6;
    int r16 = lane & 15, kgrp = lane >> 4;
    int rowbase = eb * 64 + wv * 16;
    int arow = rowbase + r16; if (arow >= n) arow = n - 1;
    const float* xr = x_int + (size_t)arow * 32 + kgrp * 8;
    float4 xa = *(const float4*)xr, xb = *(const float4*)(xr + 4);
    bf16x8 af;
    af[0] = (__bf16)xa.x; af[1] = (__bf16)xa.y; af[2] = (__bf16)xa.z; af[3] = (__bf16)xa.w;
    af[4] = (__bf16)xb.x; af[5] = (__bf16)xb.y; af[6] = (__bf16)xb.z; af[7] = (__bf16)xb.w;
    __syncthreads();
#pragma unroll
    for (int ct = 0; ct < 8; ++ct) {
        int c = ct * 16 + r16;
        bf16x8 bf = *(const bf16x8*)(WB + c * 80 + kgrp * 16);
        f32x4 acc = { 0.f, 0.f, 0.f, 0.f };
        acc = __builtin_amdgcn_mfma_f32_16x16x32_bf16(af, bf, acc, 0, 0, 0);
        float bb = b_int[c];
#pragma unroll
        for (int i = 0; i < 4; ++i) {
            int grow = rowbase + kgrp * 4 + i;
            if (grow < n) hb[(size_t)grow * H + c] = f2bf(acc[i] + bb);
        }
    }
}

// ================= 3-phase scan (spatial) =================
__global__ __launch_bounds__(256) void k_scan1(const int* __restrict__ cnt, int n,
                                               int* __restrict__ partial)
{
    int blk = blockIdx.x;
    int chunk = (n + SB - 1) / SB;
    int lo = blk * chunk, hi = min(lo + chunk, n);
    int s = 0;
    for (int i = lo + threadIdx.x; i < hi; i += 256) s += cnt[i];
    __shared__ int sh[256];
    sh[threadIdx.x] = s; __syncthreads();
    for (int d = 128; d; d >>= 1) {
        if (threadIdx.x < d) sh[threadIdx.x] += sh[threadIdx.x + d];
        __syncthreads();
    }
    if (threadIdx.x == 0) partial[blk] = sh[0];
}

__global__ __launch_bounds__(64) void k_scan2(int* __restrict__ partial,
                                              int* __restrict__ rowptr, int n, int E0)
{
    int lane = threadIdx.x;
    int v = partial[lane];
    int inc = v;
    for (int d = 1; d < 64; d <<= 1) {
        int t = __shfl_up(inc, d);
        if (lane >= d) inc += t;
    }
    partial[lane] = inc - v;
    if (lane == 0) rowptr[n] = E0;
}

__global__ __launch_bounds__(256) void k_scan3(const int* __restrict__ cnt,
                                               const int* __restrict__ partial,
                                               int* __restrict__ rowptr,
                                               float* __restrict__ recip, int n)
{
    int blk = blockIdx.x;
    int chunk = (n + SB - 1) / SB;
    int lo = blk * chunk, hi = min(lo + chunk, n);
    int per = (chunk + 255) >> 8;
    int tlo = min(lo + threadIdx.x * per, hi);
    int thi = min(tlo + per, hi);
    int s = 0;
    for (int i = tlo; i < thi; ++i) s += cnt[i];
    __shared__ int sh[256];
    sh[threadIdx.x] = s; __syncthreads();
    for (int d = 1; d < 256; d <<= 1) {
        int t = (threadIdx.x >= d) ? sh[threadIdx.x - d] : 0;
        __syncthreads();
        sh[threadIdx.x] += t;
        __syncthreads();
    }
    int run = partial[blk] + sh[threadIdx.x] - s;
    for (int i = tlo; i < thi; ++i) {
        int c = cnt[i];
        rowptr[i] = run;
        recip[i] = (c > 0) ? 1.0f / (float)c : 0.0f;
        run += c;
    }
}

// ================= fused tail: spatial CSR fill + stat GEMM =================
__global__ __launch_bounds__(256) void k_tail(
    const int* __restrict__ s0, int E0,
    const int* __restrict__ rowptr, const int* __restrict__ seq, int* __restrict__ col, int Bfill,
    const float* __restrict__ XL, const float* __restrict__ XS, const float* __restrict__ XI,
    const float* __restrict__ CNT1, const float* __restrict__ CNT2, const float* __restrict__ CNT3,
    const float* __restrict__ WL, const float* __restrict__ WSn, const float* __restrict__ WI,
    const float* __restrict__ bL, const float* __restrict__ bS, const float* __restrict__ bI,
    unsigned short* __restrict__ statb, int n)
{
    __shared__ float Wc[32][128];
    __shared__ float xs[8][32];
    __shared__ float msk[8][3];

    int b = blockIdx.x;
    int t = threadIdx.x;
    if (b < Bfill) {
        int e = b * 256 + t;
        if (e >= E0) return;
        int tg = s0[E0 + e];
        col[rowptr[tg] + seq[e]] = s0[e];
        return;
    }
    int sb = b - Bfill;

    for (int i = t; i < 16 * 128; i += 256) Wc[i >> 7][i & 127] = WL[i];
    for (int i = t; i < 8 * 128; i += 256)  Wc[16 + (i >> 7)][i & 127] = WSn[i];
    for (int i = t; i < 8 * 128; i += 256)  Wc[24 + (i >> 7)][i & 127] = WI[i];
    {
        int rr = t >> 5, k = t & 31;
        int rrow = sb * 8 + rr; if (rrow >= n) rrow = n - 1;
        float v, c;
        if (k < 16) {
            c = CNT1[rrow];
            v = XL[(size_t)rrow * 16 + k];
            if (k == 0) msk[rr][0] = (c > 0.f) ? 1.f : 0.f;
        } else if (k < 24) {
            c = CNT2[rrow];
            v = XS[(size_t)rrow * 8 + (k - 16)];
            if (k == 16) msk[rr][1] = (c > 0.f) ? 1.f : 0.f;
        } else {
            c = CNT3[rrow];
            v = XI[(size_t)rrow * 8 + (k - 24)];
            if (k == 24) msk[rr][2] = (c > 0.f) ? 1.f : 0.f;
        }
        float r = (c > 0.f) ? 1.0f / c : 0.0f;
        xs[rr][k] = v * r;
    }
    __syncthreads();
    int rl = t >> 5, c4 = (t & 31) << 2;
    int row = sb * 8 + rl;
    float a0 = 0.f, a1 = 0.f, a2 = 0.f, a3 = 0.f;
#pragma unroll
    for (int k = 0; k < 32; ++k) {
        float xv = xs[rl][k];
        a0 += xv * Wc[k][c4 + 0]; a1 += xv * Wc[k][c4 + 1];
        a2 += xv * Wc[k][c4 + 2]; a3 += xv * Wc[k][c4 + 3];
    }
    if (row < n) {
        float mL = msk[rl][0], mS = msk[rl][1], mI = msk[rl][2];
        uint2 res;
        res.x = pack2(a0 + mL * bL[c4 + 0] + mS * bS[c4 + 0] + mI * bI[c4 + 0],
                      a1 + mL * bL[c4 + 1] + mS * bS[c4 + 1] + mI * bI[c4 + 1]);
        res.y = pack2(a2 + mL * bL[c4 + 2] + mS * bS[c4 + 2] + mI * bI[c4 + 2],
                      a3 + mL * bL[c4 + 3] + mS * bS[c4 + 3] + mI * bI[c4 + 3]);
        *(uint2*)(statb + (size_t)row * H + c4) = res;
    }
}

// ================= spatial SpMM: aggb = bf16(mean(hb_nbr) + statb) =================
__global__ __launch_bounds__(256) void k_spmm(const unsigned short* __restrict__ hsrc,
                                              const int* __restrict__ rowptr,
                                              const int* __restrict__ col,
                                              const float* __restrict__ recip,
                                              const unsigned short* __restrict__ statb,
                                              unsigned short* __restrict__ aggout, int n)
{
    int row = blockIdx.x * 16 + (threadIdx.x >> 4);
    if (row >= n) return;
    int q = (threadIdx.x & 15) << 3;   // 8 bf16 per lane
    int beg = rowptr[row], end = rowptr[row + 1];

    float a0 = 0.f, a1 = 0.f, a2 = 0.f, a3 = 0.f, a4 = 0.f, a5 = 0.f, a6 = 0.f, a7 = 0.f;
    int e = beg;
    for (; e + 4 <= end; e += 4) {
        int s0 = col[e], s1 = col[e + 1], s2 = col[e + 2], s3 = col[e + 3];
        uint4 v0 = *(const uint4*)(hsrc + (size_t)s0 * H + q);
        uint4 v1 = *(const uint4*)(hsrc + (size_t)s1 * H + q);
        uint4 v2 = *(const uint4*)(hsrc + (size_t)s2 * H + q);
        uint4 v3 = *(const uint4*)(hsrc + (size_t)s3 * H + q);
        acc2(v0.x, a0, a1); acc2(v0.y, a2, a3); acc2(v0.z, a4, a5); acc2(v0.w, a6, a7);
        acc2(v1.x, a0, a1); acc2(v1.y, a2, a3); acc2(v1.z, a4, a5); acc2(v1.w, a6, a7);
        acc2(v2.x, a0, a1); acc2(v2.y, a2, a3); acc2(v2.z, a4, a5); acc2(v2.w, a6, a7);
        acc2(v3.x, a0, a1); acc2(v3.y, a2, a3); acc2(v3.z, a4, a5); acc2(v3.w, a6, a7);
    }
    for (; e < end; ++e) {
        uint4 v0 = *(const uint4*)(hsrc + (size_t)col[e] * H + q);
        acc2(v0.x, a0, a1); acc2(v0.y, a2, a3); acc2(v0.z, a4, a5); acc2(v0.w, a6, a7);
    }

    float r = recip[row];
    size_t o = (size_t)row * H + q;
    uint4 sv = *(const uint4*)(statb + o);
    uint4 w;
    w.x = pack2(a0 * r + bflo(sv.x), a1 * r + bfhi(sv.x));
    w.y = pack2(a2 * r + bflo(sv.y), a3 * r + bfhi(sv.y));
    w.z = pack2(a4 * r + bflo(sv.z), a5 * r + bfhi(sv.z));
    w.w = pack2(a6 * r + bflo(sv.w), a7 * r + bfhi(sv.w));
    *(uint4*)(aggout + o) = w;
}

// ================= MFMA layer: elu([h|agg] @ [Wself;Wrel] + b) =================
template<int LAST>
__global__ __launch_bounds__(256) void k_layer(const unsigned short* __restrict__ hb,
                                               const unsigned short* __restrict__ aggb,
                                               const float* __restrict__ Ws,
                                               const float* __restrict__ Wr,
                                               const float* __restrict__ bias,
                                               unsigned short* __restrict__ hbout,
                                               float* __restrict__ fout, int n)
{
    __shared__ __align__(16) char BT[128 * 256 * 2];

    int tid = threadIdx.x;
    {
        int c = tid & 127, half = tid >> 7;
        for (int kc = half; kc < 32; kc += 2) {
            int kk0 = kc * 8;
            const float* Wsrc = (kk0 < 128) ? (Ws + (size_t)kk0 * H + c)
                                            : (Wr + (size_t)(kk0 - 128) * H + c);
            bf16x8 pack;
#pragma unroll
            for (int j = 0; j < 8; ++j) pack[j] = (__bf16)Wsrc[(size_t)j * H];
            int woff = c * 512 + ((kc * 16) ^ ((c & 7) << 4));
            *(bf16x8*)(BT + woff) = pack;
        }
    }

    int lane = tid & 63, wv = tid >> 6;
    int r16 = lane & 15, kgrp = lane >> 4;
    int rowbase = blockIdx.x * 64 + wv * 16;
    int arow = rowbase + r16; if (arow >= n) arow = n - 1;

    bf16x8 afrag[8];
#pragma unroll
    for (int ks = 0; ks < 8; ++ks) {
        int k0 = ks * 32 + kgrp * 8;
        const unsigned short* src = (k0 < 128) ? (hb + (size_t)arow * H + k0)
                                               : (aggb + (size_t)arow * H + (k0 - 128));
        afrag[ks] = *(const bf16x8*)src;
    }
    __syncthreads();

#pragma unroll
    for (int ct = 0; ct < 8; ++ct) {
        int c = ct * 16 + r16;
        f32x4 acc = { 0.f, 0.f, 0.f, 0.f };
#pragma unroll
        for (int ks = 0; ks < 8; ++ks) {
            int kbyte = ks * 64 + kgrp * 16;
            int off = c * 512 + (kbyte ^ ((c & 7) << 4));
            bf16x8 bfrag = *(const bf16x8*)(BT + off);
            acc = __builtin_amdgcn_mfma_f32_16x16x32_bf16(afrag[ks], bfrag, acc, 0, 0, 0);
        }
        float bb = bias[c];
#pragma unroll
        for (int i = 0; i < 4; ++i) {
            int grow = rowbase + kgrp * 4 + i;
            if (grow < n) {
                float v = acc[i] + bb;
                v = (v > 0.f) ? v : (expf(v) - 1.f);
                if (LAST) fout[(size_t)grow * H + c] = v;
                else      hbout[(size_t)grow * H + c] = f2bf(v);
            }
        }
    }
}

extern "C" void kernel_launch(void* const* d_in, const int* in_sizes, int n_in,
                              void* d_out, int out_size, void* d_ws, size_t ws_size,
                              hipStream_t stream)
{
    const float* x_int  = (const float*)d_in[0];
    const float* x_lane = (const float*)d_in[1];
    const float* x_sens = (const float*)d_in[2];
    const float* x_inj  = (const float*)d_in[3];
    const int*   e_sp   = (const int*)d_in[4];
    const int*   e_fl   = (const int*)d_in[5];
    const int*   e_fs   = (const int*)d_in[6];
    const int*   e_in   = (const int*)d_in[7];
    const float* W_int  = (const float*)d_in[8];
    const float* b_int  = (const float*)d_in[9];
    const float* W_lane = (const float*)d_in[10];
    const float* b_lane = (const float*)d_in[11];
    const float* W_sens = (const float*)d_in[12];
    const float* b_sens = (const float*)d_in[13];
    const float* W_inj  = (const float*)d_in[14];
    const float* b_inj  = (const float*)d_in[15];
    const float* self_W = (const float*)d_in[16];
    const float* self_b = (const float*)d_in[17];
    const float* rel_W  = (const float*)d_in[18];

    const int n = in_sizes[0] / 32;
    const int E0 = in_sizes[4] / 2, E1 = in_sizes[5] / 2, E2 = in_sizes[6] / 2, E3 = in_sizes[7] / 2;

    float* out = (float*)d_out;

    // ---- workspace carve ----
    char* base = (char*)d_ws;
    size_t off = 0;
    auto carve = [&](size_t bytes) { char* p = base + off; off += (bytes + 15) & ~(size_t)15; return p; };
    unsigned short* hb_a  = (unsigned short*)carve((size_t)n * H * 2);
    unsigned short* hb_b  = (unsigned short*)carve((size_t)n * H * 2);
    unsigned short* aggb  = (unsigned short*)carve((size_t)n * H * 2);
    unsigned short* statb = (unsigned short*)carve((size_t)n * H * 2);
    // zero-init region: XL(16n) XS(8n) XI(8n) CNT1-3(3n) f32 + cnt0(n int) = 36n floats
    float* Z = (float*)carve((size_t)n * 36 * 4);
    float* XL   = Z;
    float* XS   = Z + (size_t)n * 16;
    float* XI   = Z + (size_t)n * 24;
    float* CNT1 = Z + (size_t)n * 32;
    float* CNT2 = CNT1 + n;
    float* CNT3 = CNT2 + n;
    int*   cnt0 = (int*)(CNT3 + n);
    float* recip0 = (float*)carve((size_t)n * 4);
    int* rowptr  = (int*)carve((size_t)(n + 1) * 4);
    int* partial = (int*)carve((size_t)SB * 4);
    int* seq     = (int*)carve((size_t)E0 * 4);
    int* col0    = (int*)carve((size_t)E0 * 4);

    // ---- grid ranges for fused front kernel ----
    int G1 = (E1 + 15) / 16;    // lane scatter (16 lanes/edge)
    int G2 = (E2 + 31) / 32;    // sens scatter (8 lanes/edge)
    int G3 = (E3 + 31) / 32;    // inj scatter
    int G4 = (E0 + 255) / 256;  // spatial count
    int G5 = (n + 63) / 64;     // encoder
    int g1 = G1, g2 = g1 + G2, g3 = g2 + G3, g4 = g3 + G4;
    int Btot = g4 + G5;
    int chunk = (Btot + NSLICE - 1) / NSLICE;
    int Bpad = chunk * NSLICE;

    hipMemsetAsync(Z, 0, (size_t)n * 36 * 4, stream);
    k_front<<<Bpad, 256, 0, stream>>>(e_sp, e_fl, e_fs, e_in, x_lane, x_sens, x_inj,
                                      x_int, W_int, b_int,
                                      E0, E1, E2, E3, g1, g2, g3, g4, Btot, chunk,
                                      XL, XS, XI, CNT1, CNT2, CNT3,
                                      cnt0, seq, hb_a, n);

    // ---- spatial CSR scans ----
    k_scan1<<<SB, 256, 0, stream>>>(cnt0, n, partial);
    k_scan2<<<1, 64, 0, stream>>>(partial, rowptr, n, E0);
    k_scan3<<<SB, 256, 0, stream>>>(cnt0, partial, rowptr, recip0, n);

    // ---- fused tail: fill + stat ----
    int Bfill = (E0 + 255) / 256;
    int Bstat = (n + 7) / 8;
    k_tail<<<Bfill + Bstat, 256, 0, stream>>>(e_sp, E0, rowptr, seq, col0, Bfill,
                                              XL, XS, XI, CNT1, CNT2, CNT3,
                                              W_lane, W_sens, W_inj,
                                              b_lane, b_sens, b_inj, statb, n);

    // ---- 3 layers ----
    const int spmm_grid = (n + 15) / 16;
    const int layer_grid = (n + 63) / 64;
    unsigned short* cur = hb_a;
    unsigned short* nxt = hb_b;
    for (int l = 0; l < 3; ++l) {
        k_spmm<<<spmm_grid, 256, 0, stream>>>(cur, rowptr, col0, recip0, statb, aggb, n);
        const float* Ws = self_W + (size_t)l * H * H;
        const float* Wr = rel_W  + (size_t)l * H * H;
        const float* bb = self_b + (size_t)l * H;
        if (l == 2)
            k_layer<1><<<layer_grid, 256, 0, stream>>>(cur, aggb, Ws, Wr, bb, nullptr, out, n);
        else
            k_layer<0><<<layer_grid, 256, 0, stream>>>(cur, aggb, Ws, Wr, bb, nxt, nullptr, n);
        unsigned short* t = cur; cur = nxt; nxt = t;
    }
}

// Round 13
// 365.861 us; speedup vs baseline: 1.1848x; 1.1848x over previous
//
#include <hip/hip_runtime.h>
#include <hip/hip_bf16.h>
#include <math.h>

#define H 128
#define SB 64        // scan blocks (spatial relation)
#define NB_SCAT 1024 // persistent scatter blocks
#define NB_CNT  256  // persistent spatial-count blocks

typedef float f32x4 __attribute__((ext_vector_type(4)));
typedef __bf16 bf16x8 __attribute__((ext_vector_type(8)));

__device__ __forceinline__ unsigned short f2bf(float f) {
    return __builtin_bit_cast(unsigned short, (__bf16)f);
}
__device__ __forceinline__ unsigned pack2(float lo, float hi) {
    return (unsigned)f2bf(lo) | ((unsigned)f2bf(hi) << 16);
}
__device__ __forceinline__ void acc2(unsigned u, float& a, float& b) {
    union { unsigned u; float f; } x, y;
    x.u = u << 16; y.u = u & 0xffff0000u;
    a += x.f; b += y.f;
}
__device__ __forceinline__ float bflo(unsigned u) {
    union { unsigned u; float f; } x; x.u = u << 16; return x.f;
}
__device__ __forceinline__ float bfhi(unsigned u) {
    union { unsigned u; float f; } x; x.u = u & 0xffff0000u; return x.f;
}

// ================= fused front: persistent co-resident roles =================
// blocks [0,NB_SCAT)                : static scatter, contiguous lane-item chunks
// blocks [NB_SCAT,NB_SCAT+NB_CNT)   : spatial count+seq, contiguous edge chunks
// blocks [NB_SCAT+NB_CNT, ...)      : x_int MFMA encoder
__global__ __launch_bounds__(256) void k_front(
    const int* __restrict__ s0, const int* __restrict__ s1,
    const int* __restrict__ s2, const int* __restrict__ s3,
    const float* __restrict__ xL, const float* __restrict__ xS, const float* __restrict__ xI,
    const float* __restrict__ x_int, const float* __restrict__ W_int, const float* __restrict__ b_int,
    int E0, int E1, int E2, int E3,
    float* __restrict__ XL, float* __restrict__ XS, float* __restrict__ XI,
    float* __restrict__ CNT1, float* __restrict__ CNT2, float* __restrict__ CNT3,
    int* __restrict__ cnt0, int* __restrict__ seq,
    unsigned short* __restrict__ hb, int n)
{
    __shared__ __align__(16) char WB[128 * 80];   // encoder blocks only
    int b = blockIdx.x;
    int tid = threadIdx.x;

    if (b < NB_SCAT) {
        // ---- static scatter: lane-items [e*D+d] concatenated over 3 relations ----
        const int W1 = E1 * 16, W2 = E2 * 8;
        const int Wtot = W1 + W2 + E3 * 8;
        const int per = (Wtot + NB_SCAT - 1) / NB_SCAT;
        int lo = b * per;
        int hi = min(lo + per, Wtot);
        for (int i = lo + tid; i < hi; i += 256) {
            if (i < W1) {
                int e = i >> 4, d = i & 15;
                int src = s1[e], tgt = s1[E1 + e];
                unsafeAtomicAdd(&XL[(size_t)tgt * 16 + d], xL[(size_t)src * 16 + d]);
                if (d == 0) unsafeAtomicAdd(&CNT1[tgt], 1.0f);
            } else if (i < W1 + W2) {
                int j = i - W1;
                int e = j >> 3, d = j & 7;
                int src = s2[e], tgt = s2[E2 + e];
                unsafeAtomicAdd(&XS[(size_t)tgt * 8 + d], xS[(size_t)src * 8 + d]);
                if (d == 0) unsafeAtomicAdd(&CNT2[tgt], 1.0f);
            } else {
                int j = i - W1 - W2;
                int e = j >> 3, d = j & 7;
                int src = s3[e], tgt = s3[E3 + e];
                unsafeAtomicAdd(&XI[(size_t)tgt * 8 + d], xI[(size_t)src * 8 + d]);
                if (d == 0) unsafeAtomicAdd(&CNT3[tgt], 1.0f);
            }
        }
        return;
    }
    if (b < NB_SCAT + NB_CNT) {
        // ---- spatial count + seq, contiguous chunk ----
        int bc = b - NB_SCAT;
        int per = (E0 + NB_CNT - 1) / NB_CNT;
        int lo = bc * per;
        int hi = min(lo + per, E0);
        for (int e = lo + tid; e < hi; e += 256)
            seq[e] = atomicAdd(&cnt0[s0[E0 + e]], 1);
        return;
    }

    // ---- x_int MFMA encoder (K=32) ----
    int eb = b - (NB_SCAT + NB_CNT);
    {
        int c = tid & 127, khalf = tid >> 7;
        for (int kk = 0; kk < 16; ++kk) {
            int k = khalf * 16 + kk;
            *(unsigned short*)(WB + c * 80 + k * 2) = f2bf(W_int[(size_t)k * H + c]);
        }
    }
    int lane = tid & 63, wv = tid >> 6;
    int r16 = lane & 15, kgrp = lane >> 4;
    int rowbase = eb * 64 + wv * 16;
    int arow = rowbase + r16; if (arow >= n) arow = n - 1;
    const float* xr = x_int + (size_t)arow * 32 + kgrp * 8;
    float4 xa = *(const float4*)xr, xb = *(const float4*)(xr + 4);
    bf16x8 af;
    af[0] = (__bf16)xa.x; af[1] = (__bf16)xa.y; af[2] = (__bf16)xa.z; af[3] = (__bf16)xa.w;
    af[4] = (__bf16)xb.x; af[5] = (__bf16)xb.y; af[6] = (__bf16)xb.z; af[7] = (__bf16)xb.w;
    __syncthreads();
#pragma unroll
    for (int ct = 0; ct < 8; ++ct) {
        int c = ct * 16 + r16;
        bf16x8 bf = *(const bf16x8*)(WB + c * 80 + kgrp * 16);
        f32x4 acc = { 0.f, 0.f, 0.f, 0.f };
        acc = __builtin_amdgcn_mfma_f32_16x16x32_bf16(af, bf, acc, 0, 0, 0);
        float bb = b_int[c];
#pragma unroll
    for (int i = 0; i < 4; ++i) {
            int grow = rowbase + kgrp * 4 + i;
            if (grow < n) hb[(size_t)grow * H + c] = f2bf(acc[i] + bb);
        }
    }
}

// ================= 3-phase scan (spatial) =================
__global__ __launch_bounds__(256) void k_scan1(const int* __restrict__ cnt, int n,
                                               int* __restrict__ partial)
{
    int blk = blockIdx.x;
    int chunk = (n + SB - 1) / SB;
    int lo = blk * chunk, hi = min(lo + chunk, n);
    int s = 0;
    for (int i = lo + threadIdx.x; i < hi; i += 256) s += cnt[i];
    __shared__ int sh[256];
    sh[threadIdx.x] = s; __syncthreads();
    for (int d = 128; d; d >>= 1) {
        if (threadIdx.x < d) sh[threadIdx.x] += sh[threadIdx.x + d];
        __syncthreads();
    }
    if (threadIdx.x == 0) partial[blk] = sh[0];
}

__global__ __launch_bounds__(64) void k_scan2(int* __restrict__ partial,
                                              int* __restrict__ rowptr, int n, int E0)
{
    int lane = threadIdx.x;
    int v = partial[lane];
    int inc = v;
    for (int d = 1; d < 64; d <<= 1) {
        int t = __shfl_up(inc, d);
        if (lane >= d) inc += t;
    }
    partial[lane] = inc - v;
    if (lane == 0) rowptr[n] = E0;
}

__global__ __launch_bounds__(256) void k_scan3(const int* __restrict__ cnt,
                                               const int* __restrict__ partial,
                                               int* __restrict__ rowptr,
                                               float* __restrict__ recip, int n)
{
    int blk = blockIdx.x;
    int chunk = (n + SB - 1) / SB;
    int lo = blk * chunk, hi = min(lo + chunk, n);
    int per = (chunk + 255) >> 8;
    int tlo = min(lo + threadIdx.x * per, hi);
    int thi = min(tlo + per, hi);
    int s = 0;
    for (int i = tlo; i < thi; ++i) s += cnt[i];
    __shared__ int sh[256];
    sh[threadIdx.x] = s; __syncthreads();
    for (int d = 1; d < 256; d <<= 1) {
        int t = (threadIdx.x >= d) ? sh[threadIdx.x - d] : 0;
        __syncthreads();
        sh[threadIdx.x] += t;
        __syncthreads();
    }
    int run = partial[blk] + sh[threadIdx.x] - s;
    for (int i = tlo; i < thi; ++i) {
        int c = cnt[i];
        rowptr[i] = run;
        recip[i] = (c > 0) ? 1.0f / (float)c : 0.0f;
        run += c;
    }
}

// ================= fused tail: spatial CSR fill + stat GEMM =================
__global__ __launch_bounds__(256) void k_tail(
    const int* __restrict__ s0, int E0,
    const int* __restrict__ rowptr, const int* __restrict__ seq, int* __restrict__ col, int Bfill,
    const float* __restrict__ XL, const float* __restrict__ XS, const float* __restrict__ XI,
    const float* __restrict__ CNT1, const float* __restrict__ CNT2, const float* __restrict__ CNT3,
    const float* __restrict__ WL, const float* __restrict__ WSn, const float* __restrict__ WI,
    const float* __restrict__ bL, const float* __restrict__ bS, const float* __restrict__ bI,
    unsigned short* __restrict__ statb, int n)
{
    __shared__ float Wc[32][128];
    __shared__ float xs[8][32];
    __shared__ float msk[8][3];

    int b = blockIdx.x;
    int t = threadIdx.x;
    if (b < Bfill) {
        int e = b * 256 + t;
        if (e >= E0) return;
        int tg = s0[E0 + e];
        col[rowptr[tg] + seq[e]] = s0[e];
        return;
    }
    int sb = b - Bfill;

    for (int i = t; i < 16 * 128; i += 256) Wc[i >> 7][i & 127] = WL[i];
    for (int i = t; i < 8 * 128; i += 256)  Wc[16 + (i >> 7)][i & 127] = WSn[i];
    for (int i = t; i < 8 * 128; i += 256)  Wc[24 + (i >> 7)][i & 127] = WI[i];
    {
        int rr = t >> 5, k = t & 31;
        int rrow = sb * 8 + rr; if (rrow >= n) rrow = n - 1;
        float v, c;
        if (k < 16) {
            c = CNT1[rrow];
            v = XL[(size_t)rrow * 16 + k];
            if (k == 0) msk[rr][0] = (c > 0.f) ? 1.f : 0.f;
        } else if (k < 24) {
            c = CNT2[rrow];
            v = XS[(size_t)rrow * 8 + (k - 16)];
            if (k == 16) msk[rr][1] = (c > 0.f) ? 1.f : 0.f;
        } else {
            c = CNT3[rrow];
            v = XI[(size_t)rrow * 8 + (k - 24)];
            if (k == 24) msk[rr][2] = (c > 0.f) ? 1.f : 0.f;
        }
        float r = (c > 0.f) ? 1.0f / c : 0.0f;
        xs[rr][k] = v * r;
    }
    __syncthreads();
    int rl = t >> 5, c4 = (t & 31) << 2;
    int row = sb * 8 + rl;
    float a0 = 0.f, a1 = 0.f, a2 = 0.f, a3 = 0.f;
#pragma unroll
    for (int k = 0; k < 32; ++k) {
        float xv = xs[rl][k];
        a0 += xv * Wc[k][c4 + 0]; a1 += xv * Wc[k][c4 + 1];
        a2 += xv * Wc[k][c4 + 2]; a3 += xv * Wc[k][c4 + 3];
    }
    if (row < n) {
        float mL = msk[rl][0], mS = msk[rl][1], mI = msk[rl][2];
        uint2 res;
        res.x = pack2(a0 + mL * bL[c4 + 0] + mS * bS[c4 + 0] + mI * bI[c4 + 0],
                      a1 + mL * bL[c4 + 1] + mS * bS[c4 + 1] + mI * bI[c4 + 1]);
        res.y = pack2(a2 + mL * bL[c4 + 2] + mS * bS[c4 + 2] + mI * bI[c4 + 2],
                      a3 + mL * bL[c4 + 3] + mS * bS[c4 + 3] + mI * bI[c4 + 3]);
        *(uint2*)(statb + (size_t)row * H + c4) = res;
    }
}

// ================= spatial SpMM: aggb = bf16(mean(hb_nbr) + statb) =================
__global__ __launch_bounds__(256) void k_spmm(const unsigned short* __restrict__ hsrc,
                                              const int* __restrict__ rowptr,
                                              const int* __restrict__ col,
                                              const float* __restrict__ recip,
                                              const unsigned short* __restrict__ statb,
                                              unsigned short* __restrict__ aggout, int n)
{
    int row = blockIdx.x * 16 + (threadIdx.x >> 4);
    if (row >= n) return;
    int q = (threadIdx.x & 15) << 3;   // 8 bf16 per lane
    int beg = rowptr[row], end = rowptr[row + 1];

    float a0 = 0.f, a1 = 0.f, a2 = 0.f, a3 = 0.f, a4 = 0.f, a5 = 0.f, a6 = 0.f, a7 = 0.f;
    int e = beg;
    for (; e + 4 <= end; e += 4) {
        int s0 = col[e], s1 = col[e + 1], s2 = col[e + 2], s3 = col[e + 3];
        uint4 v0 = *(const uint4*)(hsrc + (size_t)s0 * H + q);
        uint4 v1 = *(const uint4*)(hsrc + (size_t)s1 * H + q);
        uint4 v2 = *(const uint4*)(hsrc + (size_t)s2 * H + q);
        uint4 v3 = *(const uint4*)(hsrc + (size_t)s3 * H + q);
        acc2(v0.x, a0, a1); acc2(v0.y, a2, a3); acc2(v0.z, a4, a5); acc2(v0.w, a6, a7);
        acc2(v1.x, a0, a1); acc2(v1.y, a2, a3); acc2(v1.z, a4, a5); acc2(v1.w, a6, a7);
        acc2(v2.x, a0, a1); acc2(v2.y, a2, a3); acc2(v2.z, a4, a5); acc2(v2.w, a6, a7);
        acc2(v3.x, a0, a1); acc2(v3.y, a2, a3); acc2(v3.z, a4, a5); acc2(v3.w, a6, a7);
    }
    for (; e < end; ++e) {
        uint4 v0 = *(const uint4*)(hsrc + (size_t)col[e] * H + q);
        acc2(v0.x, a0, a1); acc2(v0.y, a2, a3); acc2(v0.z, a4, a5); acc2(v0.w, a6, a7);
    }

    float r = recip[row];
    size_t o = (size_t)row * H + q;
    uint4 sv = *(const uint4*)(statb + o);
    uint4 w;
    w.x = pack2(a0 * r + bflo(sv.x), a1 * r + bfhi(sv.x));
    w.y = pack2(a2 * r + bflo(sv.y), a3 * r + bfhi(sv.y));
    w.z = pack2(a4 * r + bflo(sv.z), a5 * r + bfhi(sv.z));
    w.w = pack2(a6 * r + bflo(sv.w), a7 * r + bfhi(sv.w));
    *(uint4*)(aggout + o) = w;
}

// ================= MFMA layer: elu([h|agg] @ [Wself;Wrel] + b) =================
template<int LAST>
__global__ __launch_bounds__(256) void k_layer(const unsigned short* __restrict__ hb,
                                               const unsigned short* __restrict__ aggb,
                                               const float* __restrict__ Ws,
                                               const float* __restrict__ Wr,
                                               const float* __restrict__ bias,
                                               unsigned short* __restrict__ hbout,
                                               float* __restrict__ fout, int n)
{
    __shared__ __align__(16) char BT[128 * 256 * 2];

    int tid = threadIdx.x;
    {
        int c = tid & 127, half = tid >> 7;
        for (int kc = half; kc < 32; kc += 2) {
            int kk0 = kc * 8;
            const float* Wsrc = (kk0 < 128) ? (Ws + (size_t)kk0 * H + c)
                                            : (Wr + (size_t)(kk0 - 128) * H + c);
            bf16x8 pack;
#pragma unroll
            for (int j = 0; j < 8; ++j) pack[j] = (__bf16)Wsrc[(size_t)j * H];
            int woff = c * 512 + ((kc * 16) ^ ((c & 7) << 4));
            *(bf16x8*)(BT + woff) = pack;
        }
    }

    int lane = tid & 63, wv = tid >> 6;
    int r16 = lane & 15, kgrp = lane >> 4;
    int rowbase = blockIdx.x * 64 + wv * 16;
    int arow = rowbase + r16; if (arow >= n) arow = n - 1;

    bf16x8 afrag[8];
#pragma unroll
    for (int ks = 0; ks < 8; ++ks) {
        int k0 = ks * 32 + kgrp * 8;
        const unsigned short* src = (k0 < 128) ? (hb + (size_t)arow * H + k0)
                                               : (aggb + (size_t)arow * H + (k0 - 128));
        afrag[ks] = *(const bf16x8*)src;
    }
    __syncthreads();

#pragma unroll
    for (int ct = 0; ct < 8; ++ct) {
        int c = ct * 16 + r16;
        f32x4 acc = { 0.f, 0.f, 0.f, 0.f };
#pragma unroll
        for (int ks = 0; ks < 8; ++ks) {
            int kbyte = ks * 64 + kgrp * 16;
            int off = c * 512 + (kbyte ^ ((c & 7) << 4));
            bf16x8 bfrag = *(const bf16x8*)(BT + off);
            acc = __builtin_amdgcn_mfma_f32_16x16x32_bf16(afrag[ks], bfrag, acc, 0, 0, 0);
        }
        float bb = bias[c];
#pragma unroll
        for (int i = 0; i < 4; ++i) {
            int grow = rowbase + kgrp * 4 + i;
            if (grow < n) {
                float v = acc[i] + bb;
                v = (v > 0.f) ? v : (expf(v) - 1.f);
                if (LAST) fout[(size_t)grow * H + c] = v;
                else      hbout[(size_t)grow * H + c] = f2bf(v);
            }
        }
    }
}

extern "C" void kernel_launch(void* const* d_in, const int* in_sizes, int n_in,
                              void* d_out, int out_size, void* d_ws, size_t ws_size,
                              hipStream_t stream)
{
    const float* x_int  = (const float*)d_in[0];
    const float* x_lane = (const float*)d_in[1];
    const float* x_sens = (const float*)d_in[2];
    const float* x_inj  = (const float*)d_in[3];
    const int*   e_sp   = (const int*)d_in[4];
    const int*   e_fl   = (const int*)d_in[5];
    const int*   e_fs   = (const int*)d_in[6];
    const int*   e_in   = (const int*)d_in[7];
    const float* W_int  = (const float*)d_in[8];
    const float* b_int  = (const float*)d_in[9];
    const float* W_lane = (const float*)d_in[10];
    const float* b_lane = (const float*)d_in[11];
    const float* W_sens = (const float*)d_in[12];
    const float* b_sens = (const float*)d_in[13];
    const float* W_inj  = (const float*)d_in[14];
    const float* b_inj  = (const float*)d_in[15];
    const float* self_W = (const float*)d_in[16];
    const float* self_b = (const float*)d_in[17];
    const float* rel_W  = (const float*)d_in[18];

    const int n = in_sizes[0] / 32;
    const int E0 = in_sizes[4] / 2, E1 = in_sizes[5] / 2, E2 = in_sizes[6] / 2, E3 = in_sizes[7] / 2;

    float* out = (float*)d_out;

    // ---- workspace carve ----
    char* base = (char*)d_ws;
    size_t off = 0;
    auto carve = [&](size_t bytes) { char* p = base + off; off += (bytes + 15) & ~(size_t)15; return p; };
    unsigned short* hb_a  = (unsigned short*)carve((size_t)n * H * 2);
    unsigned short* hb_b  = (unsigned short*)carve((size_t)n * H * 2);
    unsigned short* aggb  = (unsigned short*)carve((size_t)n * H * 2);
    unsigned short* statb = (unsigned short*)carve((size_t)n * H * 2);
    // zero-init region: XL(16n) XS(8n) XI(8n) CNT1-3(3n) f32 + cnt0(n int) = 36n floats
    float* Z = (float*)carve((size_t)n * 36 * 4);
    float* XL   = Z;
    float* XS   = Z + (size_t)n * 16;
    float* XI   = Z + (size_t)n * 24;
    float* CNT1 = Z + (size_t)n * 32;
    float* CNT2 = CNT1 + n;
    float* CNT3 = CNT2 + n;
    int*   cnt0 = (int*)(CNT3 + n);
    float* recip0 = (float*)carve((size_t)n * 4);
    int* rowptr  = (int*)carve((size_t)(n + 1) * 4);
    int* partial = (int*)carve((size_t)SB * 4);
    int* seq     = (int*)carve((size_t)E0 * 4);
    int* col0    = (int*)carve((size_t)E0 * 4);

    int G5 = (n + 63) / 64;     // encoder blocks

    hipMemsetAsync(Z, 0, (size_t)n * 36 * 4, stream);
    k_front<<<NB_SCAT + NB_CNT + G5, 256, 0, stream>>>(
        e_sp, e_fl, e_fs, e_in, x_lane, x_sens, x_inj,
        x_int, W_int, b_int,
        E0, E1, E2, E3,
        XL, XS, XI, CNT1, CNT2, CNT3,
        cnt0, seq, hb_a, n);

    // ---- spatial CSR scans ----
    k_scan1<<<SB, 256, 0, stream>>>(cnt0, n, partial);
    k_scan2<<<1, 64, 0, stream>>>(partial, rowptr, n, E0);
    k_scan3<<<SB, 256, 0, stream>>>(cnt0, partial, rowptr, recip0, n);

    // ---- fused tail: fill + stat ----
    int Bfill = (E0 + 255) / 256;
    int Bstat = (n + 7) / 8;
    k_tail<<<Bfill + Bstat, 256, 0, stream>>>(e_sp, E0, rowptr, seq, col0, Bfill,
                                              XL, XS, XI, CNT1, CNT2, CNT3,
                                              W_lane, W_sens, W_inj,
                                              b_lane, b_sens, b_inj, statb, n);

    // ---- 3 layers ----
    const int spmm_grid = (n + 15) / 16;
    const int layer_grid = (n + 63) / 64;
    unsigned short* cur = hb_a;
    unsigned short* nxt = hb_b;
    for (int l = 0; l < 3; ++l) {
        k_spmm<<<spmm_grid, 256, 0, stream>>>(cur, rowptr, col0, recip0, statb, aggb, n);
        const float* Ws = self_W + (size_t)l * H * H;
        const float* Wr = rel_W  + (size_t)l * H * H;
        const float* bb = self_b + (size_t)l * H;
        if (l == 2)
            k_layer<1><<<layer_grid, 256, 0, stream>>>(cur, aggb, Ws, Wr, bb, nullptr, out, n);
        else
            k_layer<0><<<layer_grid, 256, 0, stream>>>(cur, aggb, Ws, Wr, bb, nxt, nullptr, n);
        unsigned short* t = cur; cur = nxt; nxt = t;
    }
}

// Round 14
// 345.854 us; speedup vs baseline: 1.2533x; 1.0578x over previous
//
#include <hip/hip_runtime.h>
#include <hip/hip_bf16.h>
#include <math.h>

#define H 128
#define SB 64        // scan blocks (spatial relation)
#define NB_SCAT 1024 // persistent scatter blocks
#define NB_CNT  256  // persistent spatial-count blocks
#define NB_PREP 24   // weight-transpose blocks (3 layers x 8 col-groups)

typedef float f32x4 __attribute__((ext_vector_type(4)));
typedef __bf16 bf16x8 __attribute__((ext_vector_type(8)));

__device__ __forceinline__ unsigned short f2bf(float f) {
    return __builtin_bit_cast(unsigned short, (__bf16)f);
}
__device__ __forceinline__ unsigned pack2(float lo, float hi) {
    return (unsigned)f2bf(lo) | ((unsigned)f2bf(hi) << 16);
}
__device__ __forceinline__ void acc2(unsigned u, float& a, float& b) {
    union { unsigned u; float f; } x, y;
    x.u = u << 16; y.u = u & 0xffff0000u;
    a += x.f; b += y.f;
}
__device__ __forceinline__ float bflo(unsigned u) {
    union { unsigned u; float f; } x; x.u = u << 16; return x.f;
}
__device__ __forceinline__ float bfhi(unsigned u) {
    union { unsigned u; float f; } x; x.u = u & 0xffff0000u; return x.f;
}

// ================= fused front: persistent co-resident roles =================
// [0,NB_SCAT)                        : static scatter (contiguous lane-item chunks)
// [NB_SCAT, NB_SCAT+NB_CNT)          : spatial count+seq
// [NB_SCAT+NB_CNT, ... +G5)          : x_int MFMA encoder
// last NB_PREP                       : layer-weight transpose -> pre-swizzled bf16
__global__ __launch_bounds__(256) void k_front(
    const int* __restrict__ s0, const int* __restrict__ s1,
    const int* __restrict__ s2, const int* __restrict__ s3,
    const float* __restrict__ xL, const float* __restrict__ xS, const float* __restrict__ xI,
    const float* __restrict__ x_int, const float* __restrict__ W_int, const float* __restrict__ b_int,
    const float* __restrict__ self_W, const float* __restrict__ rel_W,
    int E0, int E1, int E2, int E3, int g_enc_end,
    float* __restrict__ XL, float* __restrict__ XS, float* __restrict__ XI,
    float* __restrict__ CNT1, float* __restrict__ CNT2, float* __restrict__ CNT3,
    int* __restrict__ cnt0, int* __restrict__ seq,
    unsigned short* __restrict__ hb, char* __restrict__ WTb, int n)
{
    __shared__ __align__(16) char WB[128 * 80];   // encoder blocks only
    int b = blockIdx.x;
    int tid = threadIdx.x;

    if (b < NB_SCAT) {
        // ---- static scatter: lane-items [e*D+d] concatenated over 3 relations ----
        const int W1 = E1 * 16, W2 = E2 * 8;
        const int Wtot = W1 + W2 + E3 * 8;
        const int per = (Wtot + NB_SCAT - 1) / NB_SCAT;
        int lo = b * per;
        int hi = min(lo + per, Wtot);
        for (int i = lo + tid; i < hi; i += 256) {
            if (i < W1) {
                int e = i >> 4, d = i & 15;
                int src = s1[e], tgt = s1[E1 + e];
                unsafeAtomicAdd(&XL[(size_t)tgt * 16 + d], xL[(size_t)src * 16 + d]);
                if (d == 0) unsafeAtomicAdd(&CNT1[tgt], 1.0f);
            } else if (i < W1 + W2) {
                int j = i - W1;
                int e = j >> 3, d = j & 7;
                int src = s2[e], tgt = s2[E2 + e];
                unsafeAtomicAdd(&XS[(size_t)tgt * 8 + d], xS[(size_t)src * 8 + d]);
                if (d == 0) unsafeAtomicAdd(&CNT2[tgt], 1.0f);
            } else {
                int j = i - W1 - W2;
                int e = j >> 3, d = j & 7;
                int src = s3[e], tgt = s3[E3 + e];
                unsafeAtomicAdd(&XI[(size_t)tgt * 8 + d], xI[(size_t)src * 8 + d]);
                if (d == 0) unsafeAtomicAdd(&CNT3[tgt], 1.0f);
            }
        }
        return;
    }
    if (b < NB_SCAT + NB_CNT) {
        // ---- spatial count + seq, contiguous chunk ----
        int bc = b - NB_SCAT;
        int per = (E0 + NB_CNT - 1) / NB_CNT;
        int lo = bc * per;
        int hi = min(lo + per, E0);
        for (int e = lo + tid; e < hi; e += 256)
            seq[e] = atomicAdd(&cnt0[s0[E0 + e]], 1);
        return;
    }
    if (b >= g_enc_end) {
        // ---- weight prep: transpose [Ws;Wr] -> pre-swizzled bf16 BT image ----
        int pb = b - g_enc_end;           // 0..NB_PREP-1
        int l = pb >> 3, cg = pb & 7;     // layer, col-group (16 cols)
        const float* Ws = self_W + (size_t)l * H * H;
        const float* Wr = rel_W  + (size_t)l * H * H;
        char* dst = WTb + (size_t)l * 65536;
        int c = cg * 16 + (tid & 15);
        int kcg = tid >> 4;               // 0..15
#pragma unroll
        for (int rep = 0; rep < 2; ++rep) {
            int kc = kcg * 2 + rep;       // 0..31
            int kk0 = kc * 8;
            const float* Wsrc = (kk0 < 128) ? (Ws + (size_t)kk0 * H + c)
                                            : (Wr + (size_t)(kk0 - 128) * H + c);
            bf16x8 pack;
#pragma unroll
            for (int j = 0; j < 8; ++j) pack[j] = (__bf16)Wsrc[(size_t)j * H];
            int woff = c * 512 + ((kc * 16) ^ ((c & 7) << 4));
            *(bf16x8*)(dst + woff) = pack;
        }
        return;
    }

    // ---- x_int MFMA encoder (K=32) ----
    int eb = b - (NB_SCAT + NB_CNT);
    {
        int c = tid & 127, khalf = tid >> 7;
        for (int kk = 0; kk < 16; ++kk) {
            int k = khalf * 16 + kk;
            *(unsigned short*)(WB + c * 80 + k * 2) = f2bf(W_int[(size_t)k * H + c]);
        }
    }
    int lane = tid & 63, wv = tid >> 6;
    int r16 = lane & 15, kgrp = lane >> 4;
    int rowbase = eb * 64 + wv * 16;
    int arow = rowbase + r16; if (arow >= n) arow = n - 1;
    const float* xr = x_int + (size_t)arow * 32 + kgrp * 8;
    float4 xa = *(const float4*)xr, xb = *(const float4*)(xr + 4);
    bf16x8 af;
    af[0] = (__bf16)xa.x; af[1] = (__bf16)xa.y; af[2] = (__bf16)xa.z; af[3] = (__bf16)xa.w;
    af[4] = (__bf16)xb.x; af[5] = (__bf16)xb.y; af[6] = (__bf16)xb.z; af[7] = (__bf16)xb.w;
    __syncthreads();
#pragma unroll
    for (int ct = 0; ct < 8; ++ct) {
        int c = ct * 16 + r16;
        bf16x8 bf = *(const bf16x8*)(WB + c * 80 + kgrp * 16);
        f32x4 acc = { 0.f, 0.f, 0.f, 0.f };
        acc = __builtin_amdgcn_mfma_f32_16x16x32_bf16(af, bf, acc, 0, 0, 0);
        float bb = b_int[c];
#pragma unroll
        for (int i = 0; i < 4; ++i) {
            int grow = rowbase + kgrp * 4 + i;
            if (grow < n) hb[(size_t)grow * H + c] = f2bf(acc[i] + bb);
        }
    }
}

// ================= 3-phase scan (spatial) =================
__global__ __launch_bounds__(256) void k_scan1(const int* __restrict__ cnt, int n,
                                               int* __restrict__ partial)
{
    int blk = blockIdx.x;
    int chunk = (n + SB - 1) / SB;
    int lo = blk * chunk, hi = min(lo + chunk, n);
    int s = 0;
    for (int i = lo + threadIdx.x; i < hi; i += 256) s += cnt[i];
    __shared__ int sh[256];
    sh[threadIdx.x] = s; __syncthreads();
    for (int d = 128; d; d >>= 1) {
        if (threadIdx.x < d) sh[threadIdx.x] += sh[threadIdx.x + d];
        __syncthreads();
    }
    if (threadIdx.x == 0) partial[blk] = sh[0];
}

__global__ __launch_bounds__(64) void k_scan2(int* __restrict__ partial,
                                              int* __restrict__ rowptr, int n, int E0)
{
    int lane = threadIdx.x;
    int v = partial[lane];
    int inc = v;
    for (int d = 1; d < 64; d <<= 1) {
        int t = __shfl_up(inc, d);
        if (lane >= d) inc += t;
    }
    partial[lane] = inc - v;
    if (lane == 0) rowptr[n] = E0;
}

__global__ __launch_bounds__(256) void k_scan3(const int* __restrict__ cnt,
                                               const int* __restrict__ partial,
                                               int* __restrict__ rowptr,
                                               float* __restrict__ recip, int n)
{
    int blk = blockIdx.x;
    int chunk = (n + SB - 1) / SB;
    int lo = blk * chunk, hi = min(lo + chunk, n);
    int per = (chunk + 255) >> 8;
    int tlo = min(lo + threadIdx.x * per, hi);
    int thi = min(tlo + per, hi);
    int s = 0;
    for (int i = tlo; i < thi; ++i) s += cnt[i];
    __shared__ int sh[256];
    sh[threadIdx.x] = s; __syncthreads();
    for (int d = 1; d < 256; d <<= 1) {
        int t = (threadIdx.x >= d) ? sh[threadIdx.x - d] : 0;
        __syncthreads();
        sh[threadIdx.x] += t;
        __syncthreads();
    }
    int run = partial[blk] + sh[threadIdx.x] - s;
    for (int i = tlo; i < thi; ++i) {
        int c = cnt[i];
        rowptr[i] = run;
        recip[i] = (c > 0) ? 1.0f / (float)c : 0.0f;
        run += c;
    }
}

// ================= fused tail: spatial CSR fill + stat GEMM =================
__global__ __launch_bounds__(256) void k_tail(
    const int* __restrict__ s0, int E0,
    const int* __restrict__ rowptr, const int* __restrict__ seq, int* __restrict__ col, int Bfill,
    const float* __restrict__ XL, const float* __restrict__ XS, const float* __restrict__ XI,
    const float* __restrict__ CNT1, const float* __restrict__ CNT2, const float* __restrict__ CNT3,
    const float* __restrict__ WL, const float* __restrict__ WSn, const float* __restrict__ WI,
    const float* __restrict__ bL, const float* __restrict__ bS, const float* __restrict__ bI,
    unsigned short* __restrict__ statb, int n)
{
    __shared__ float Wc[32][128];
    __shared__ float xs[8][32];
    __shared__ float msk[8][3];

    int b = blockIdx.x;
    int t = threadIdx.x;
    if (b < Bfill) {
        int e = b * 256 + t;
        if (e >= E0) return;
        int tg = s0[E0 + e];
        col[rowptr[tg] + seq[e]] = s0[e];
        return;
    }
    int sb = b - Bfill;

    for (int i = t; i < 16 * 128; i += 256) Wc[i >> 7][i & 127] = WL[i];
    for (int i = t; i < 8 * 128; i += 256)  Wc[16 + (i >> 7)][i & 127] = WSn[i];
    for (int i = t; i < 8 * 128; i += 256)  Wc[24 + (i >> 7)][i & 127] = WI[i];
    {
        int rr = t >> 5, k = t & 31;
        int rrow = sb * 8 + rr; if (rrow >= n) rrow = n - 1;
        float v, c;
        if (k < 16) {
            c = CNT1[rrow];
            v = XL[(size_t)rrow * 16 + k];
            if (k == 0) msk[rr][0] = (c > 0.f) ? 1.f : 0.f;
        } else if (k < 24) {
            c = CNT2[rrow];
            v = XS[(size_t)rrow * 8 + (k - 16)];
            if (k == 16) msk[rr][1] = (c > 0.f) ? 1.f : 0.f;
        } else {
            c = CNT3[rrow];
            v = XI[(size_t)rrow * 8 + (k - 24)];
            if (k == 24) msk[rr][2] = (c > 0.f) ? 1.f : 0.f;
        }
        float r = (c > 0.f) ? 1.0f / c : 0.0f;
        xs[rr][k] = v * r;
    }
    __syncthreads();
    int rl = t >> 5, c4 = (t & 31) << 2;
    int row = sb * 8 + rl;
    float a0 = 0.f, a1 = 0.f, a2 = 0.f, a3 = 0.f;
#pragma unroll
    for (int k = 0; k < 32; ++k) {
        float xv = xs[rl][k];
        a0 += xv * Wc[k][c4 + 0]; a1 += xv * Wc[k][c4 + 1];
        a2 += xv * Wc[k][c4 + 2]; a3 += xv * Wc[k][c4 + 3];
    }
    if (row < n) {
        float mL = msk[rl][0], mS = msk[rl][1], mI = msk[rl][2];
        uint2 res;
        res.x = pack2(a0 + mL * bL[c4 + 0] + mS * bS[c4 + 0] + mI * bI[c4 + 0],
                      a1 + mL * bL[c4 + 1] + mS * bS[c4 + 1] + mI * bI[c4 + 1]);
        res.y = pack2(a2 + mL * bL[c4 + 2] + mS * bS[c4 + 2] + mI * bI[c4 + 2],
                      a3 + mL * bL[c4 + 3] + mS * bS[c4 + 3] + mI * bI[c4 + 3]);
        *(uint2*)(statb + (size_t)row * H + c4) = res;
    }
}

// ================= spatial SpMM: aggb = bf16(mean(hb_nbr) + statb) =================
__global__ __launch_bounds__(256) void k_spmm(const unsigned short* __restrict__ hsrc,
                                              const int* __restrict__ rowptr,
                                              const int* __restrict__ col,
                                              const float* __restrict__ recip,
                                              const unsigned short* __restrict__ statb,
                                              unsigned short* __restrict__ aggout, int n)
{
    int row = blockIdx.x * 16 + (threadIdx.x >> 4);
    if (row >= n) return;
    int q = (threadIdx.x & 15) << 3;   // 8 bf16 per lane
    int beg = rowptr[row], end = rowptr[row + 1];

    float a0 = 0.f, a1 = 0.f, a2 = 0.f, a3 = 0.f, a4 = 0.f, a5 = 0.f, a6 = 0.f, a7 = 0.f;
    int e = beg;
    for (; e + 4 <= end; e += 4) {
        int s0 = col[e], s1 = col[e + 1], s2 = col[e + 2], s3 = col[e + 3];
        uint4 v0 = *(const uint4*)(hsrc + (size_t)s0 * H + q);
        uint4 v1 = *(const uint4*)(hsrc + (size_t)s1 * H + q);
        uint4 v2 = *(const uint4*)(hsrc + (size_t)s2 * H + q);
        uint4 v3 = *(const uint4*)(hsrc + (size_t)s3 * H + q);
        acc2(v0.x, a0, a1); acc2(v0.y, a2, a3); acc2(v0.z, a4, a5); acc2(v0.w, a6, a7);
        acc2(v1.x, a0, a1); acc2(v1.y, a2, a3); acc2(v1.z, a4, a5); acc2(v1.w, a6, a7);
        acc2(v2.x, a0, a1); acc2(v2.y, a2, a3); acc2(v2.z, a4, a5); acc2(v2.w, a6, a7);
        acc2(v3.x, a0, a1); acc2(v3.y, a2, a3); acc2(v3.z, a4, a5); acc2(v3.w, a6, a7);
    }
    for (; e < end; ++e) {
        uint4 v0 = *(const uint4*)(hsrc + (size_t)col[e] * H + q);
        acc2(v0.x, a0, a1); acc2(v0.y, a2, a3); acc2(v0.z, a4, a5); acc2(v0.w, a6, a7);
    }

    float r = recip[row];
    size_t o = (size_t)row * H + q;
    uint4 sv = *(const uint4*)(statb + o);
    uint4 w;
    w.x = pack2(a0 * r + bflo(sv.x), a1 * r + bfhi(sv.x));
    w.y = pack2(a2 * r + bflo(sv.y), a3 * r + bfhi(sv.y));
    w.z = pack2(a4 * r + bflo(sv.z), a5 * r + bfhi(sv.z));
    w.w = pack2(a6 * r + bflo(sv.w), a7 * r + bfhi(sv.w));
    *(uint4*)(aggout + o) = w;
}

// ================= MFMA layer: elu([h|agg] @ [Wself;Wrel] + b), pre-swizzled bf16 weights =================
template<int LAST>
__global__ __launch_bounds__(256) void k_layer(const unsigned short* __restrict__ hb,
                                               const unsigned short* __restrict__ aggb,
                                               const char* __restrict__ WTl,
                                               const float* __restrict__ bias,
                                               unsigned short* __restrict__ hbout,
                                               float* __restrict__ fout, int n)
{
    __shared__ __align__(16) char BT[128 * 256 * 2];

    int tid = threadIdx.x;
    // ---- coalesced copy of pre-swizzled weight image (64 KB) ----
#pragma unroll
    for (int i = 0; i < 16; ++i) {
        int o = i * 4096 + tid * 16;
        *(uint4*)(BT + o) = *(const uint4*)(WTl + o);
    }

    int lane = tid & 63, wv = tid >> 6;
    int r16 = lane & 15, kgrp = lane >> 4;
    int rowbase = blockIdx.x * 64 + wv * 16;
    int arow = rowbase + r16; if (arow >= n) arow = n - 1;

    bf16x8 afrag[8];
#pragma unroll
    for (int ks = 0; ks < 8; ++ks) {
        int k0 = ks * 32 + kgrp * 8;
        const unsigned short* src = (k0 < 128) ? (hb + (size_t)arow * H + k0)
                                               : (aggb + (size_t)arow * H + (k0 - 128));
        afrag[ks] = *(const bf16x8*)src;
    }
    __syncthreads();

#pragma unroll
    for (int ct = 0; ct < 8; ++ct) {
        int c = ct * 16 + r16;
        f32x4 acc = { 0.f, 0.f, 0.f, 0.f };
#pragma unroll
        for (int ks = 0; ks < 8; ++ks) {
            int kbyte = ks * 64 + kgrp * 16;
            int off = c * 512 + (kbyte ^ ((c & 7) << 4));
            bf16x8 bfrag = *(const bf16x8*)(BT + off);
            acc = __builtin_amdgcn_mfma_f32_16x16x32_bf16(afrag[ks], bfrag, acc, 0, 0, 0);
        }
        float bb = bias[c];
#pragma unroll
        for (int i = 0; i < 4; ++i) {
            int grow = rowbase + kgrp * 4 + i;
            if (grow < n) {
                float v = acc[i] + bb;
                v = (v > 0.f) ? v : (expf(v) - 1.f);
                if (LAST) fout[(size_t)grow * H + c] = v;
                else      hbout[(size_t)grow * H + c] = f2bf(v);
            }
        }
    }
}

extern "C" void kernel_launch(void* const* d_in, const int* in_sizes, int n_in,
                              void* d_out, int out_size, void* d_ws, size_t ws_size,
                              hipStream_t stream)
{
    const float* x_int  = (const float*)d_in[0];
    const float* x_lane = (const float*)d_in[1];
    const float* x_sens = (const float*)d_in[2];
    const float* x_inj  = (const float*)d_in[3];
    const int*   e_sp   = (const int*)d_in[4];
    const int*   e_fl   = (const int*)d_in[5];
    const int*   e_fs   = (const int*)d_in[6];
    const int*   e_in   = (const int*)d_in[7];
    const float* W_int  = (const float*)d_in[8];
    const float* b_int  = (const float*)d_in[9];
    const float* W_lane = (const float*)d_in[10];
    const float* b_lane = (const float*)d_in[11];
    const float* W_sens = (const float*)d_in[12];
    const float* b_sens = (const float*)d_in[13];
    const float* W_inj  = (const float*)d_in[14];
    const float* b_inj  = (const float*)d_in[15];
    const float* self_W = (const float*)d_in[16];
    const float* self_b = (const float*)d_in[17];
    const float* rel_W  = (const float*)d_in[18];

    const int n = in_sizes[0] / 32;
    const int E0 = in_sizes[4] / 2, E1 = in_sizes[5] / 2, E2 = in_sizes[6] / 2, E3 = in_sizes[7] / 2;

    float* out = (float*)d_out;

    // ---- workspace carve ----
    char* base = (char*)d_ws;
    size_t off = 0;
    auto carve = [&](size_t bytes) { char* p = base + off; off += (bytes + 15) & ~(size_t)15; return p; };
    unsigned short* hb_a  = (unsigned short*)carve((size_t)n * H * 2);
    unsigned short* hb_b  = (unsigned short*)carve((size_t)n * H * 2);
    unsigned short* aggb  = (unsigned short*)carve((size_t)n * H * 2);
    unsigned short* statb = (unsigned short*)carve((size_t)n * H * 2);
    // zero-init region: XL(16n) XS(8n) XI(8n) CNT1-3(3n) f32 + cnt0(n int) = 36n floats
    float* Z = (float*)carve((size_t)n * 36 * 4);
    float* XL   = Z;
    float* XS   = Z + (size_t)n * 16;
    float* XI   = Z + (size_t)n * 24;
    float* CNT1 = Z + (size_t)n * 32;
    float* CNT2 = CNT1 + n;
    float* CNT3 = CNT2 + n;
    int*   cnt0 = (int*)(CNT3 + n);
    float* recip0 = (float*)carve((size_t)n * 4);
    int* rowptr  = (int*)carve((size_t)(n + 1) * 4);
    int* partial = (int*)carve((size_t)SB * 4);
    int* seq     = (int*)carve((size_t)E0 * 4);
    int* col0    = (int*)carve((size_t)E0 * 4);
    char* WTb    = carve((size_t)3 * 65536);   // pre-swizzled bf16 weight images

    int G5 = (n + 63) / 64;     // encoder blocks
    int g_enc_end = NB_SCAT + NB_CNT + G5;

    hipMemsetAsync(Z, 0, (size_t)n * 36 * 4, stream);
    k_front<<<g_enc_end + NB_PREP, 256, 0, stream>>>(
        e_sp, e_fl, e_fs, e_in, x_lane, x_sens, x_inj,
        x_int, W_int, b_int, self_W, rel_W,
        E0, E1, E2, E3, g_enc_end,
        XL, XS, XI, CNT1, CNT2, CNT3,
        cnt0, seq, hb_a, WTb, n);

    // ---- spatial CSR scans ----
    k_scan1<<<SB, 256, 0, stream>>>(cnt0, n, partial);
    k_scan2<<<1, 64, 0, stream>>>(partial, rowptr, n, E0);
    k_scan3<<<SB, 256, 0, stream>>>(cnt0, partial, rowptr, recip0, n);

    // ---- fused tail: fill + stat ----
    int Bfill = (E0 + 255) / 256;
    int Bstat = (n + 7) / 8;
    k_tail<<<Bfill + Bstat, 256, 0, stream>>>(e_sp, E0, rowptr, seq, col0, Bfill,
                                              XL, XS, XI, CNT1, CNT2, CNT3,
                                              W_lane, W_sens, W_inj,
                                              b_lane, b_sens, b_inj, statb, n);

    // ---- 3 layers ----
    const int spmm_grid = (n + 15) / 16;
    const int layer_grid = (n + 63) / 64;
    unsigned short* cur = hb_a;
    unsigned short* nxt = hb_b;
    for (int l = 0; l < 3; ++l) {
        k_spmm<<<spmm_grid, 256, 0, stream>>>(cur, rowptr, col0, recip0, statb, aggb, n);
        const char* WTl = WTb + (size_t)l * 65536;
        const float* bb = self_b + (size_t)l * H;
        if (l == 2)
            k_layer<1><<<layer_grid, 256, 0, stream>>>(cur, aggb, WTl, bb, nullptr, out, n);
        else
            k_layer<0><<<layer_grid, 256, 0, stream>>>(cur, aggb, WTl, bb, nxt, nullptr, n);
        unsigned short* t = cur; cur = nxt; nxt = t;
    }
}